// Round 1
// baseline (14924.181 us; speedup 1.0000x reference)
//
#include <hip/hip_runtime.h>
#include <cstddef>

#define BB 256
#define TT 224
#define II 224
#define HH 1024
#define OO 4

__global__ void zero_kernel(float* __restrict__ p, int n) {
    int i = blockIdx.x * blockDim.x + threadIdx.x;
    if (i < n) p[i] = 0.f;
}

// grid (8, 32): blockIdx.x -> batch-row tile (32 rows), blockIdx.y -> h-col tile (32 cols)
// block: 256 threads, each computes a 2x2 micro-tile.
__global__ __launch_bounds__(256) void rnn_step(
    const float* __restrict__ x,       // (B, T, I)
    const float* __restrict__ W_ih,    // (H, I)
    const float* __restrict__ W_hh,    // (H, H)
    const float* __restrict__ b_ih,    // (H)
    const float* __restrict__ b_hh,    // (H)
    const float* __restrict__ h_prev,  // (B, H)
    float* __restrict__ h_next,        // (B, H)
    int t)
{
    __shared__ float As[32][33];   // +1 pad: conflict-free
    __shared__ float Bs[32][33];
    const int r0 = blockIdx.x * 32;
    const int c0 = blockIdx.y * 32;
    const int tid = threadIdx.x;
    const int tr = tid >> 4;   // 0..15
    const int tc = tid & 15;   // 0..15

    float acc00 = 0.f, acc01 = 0.f, acc10 = 0.f, acc11 = 0.f;

    // ---- input projection: K over I=224 ----
    for (int kb = 0; kb < II; kb += 32) {
        #pragma unroll
        for (int l = 0; l < 4; ++l) {
            int idx = tid + l * 256;
            int r = idx >> 5, k = idx & 31;
            As[r][k] = x[((size_t)(r0 + r) * TT + t) * II + kb + k];
            Bs[r][k] = W_ih[(size_t)(c0 + r) * II + kb + k];
        }
        __syncthreads();
        #pragma unroll 8
        for (int k = 0; k < 32; ++k) {
            float a0 = As[2*tr][k],   a1 = As[2*tr+1][k];
            float b0 = Bs[2*tc][k],   b1 = Bs[2*tc+1][k];
            acc00 += a0 * b0; acc01 += a0 * b1;
            acc10 += a1 * b0; acc11 += a1 * b1;
        }
        __syncthreads();
    }

    // ---- recurrent part: K over H=1024 ----
    for (int kb = 0; kb < HH; kb += 32) {
        #pragma unroll
        for (int l = 0; l < 4; ++l) {
            int idx = tid + l * 256;
            int r = idx >> 5, k = idx & 31;
            As[r][k] = h_prev[(size_t)(r0 + r) * HH + kb + k];
            Bs[r][k] = W_hh[(size_t)(c0 + r) * HH + kb + k];
        }
        __syncthreads();
        #pragma unroll 8
        for (int k = 0; k < 32; ++k) {
            float a0 = As[2*tr][k],   a1 = As[2*tr+1][k];
            float b0 = Bs[2*tc][k],   b1 = Bs[2*tc+1][k];
            acc00 += a0 * b0; acc01 += a0 * b1;
            acc10 += a1 * b0; acc11 += a1 * b1;
        }
        __syncthreads();
    }

    // ---- epilogue: bias + tanh ----
    const int r = r0 + 2 * tr;
    const int c = c0 + 2 * tc;
    const float bias0 = b_ih[c]     + b_hh[c];
    const float bias1 = b_ih[c + 1] + b_hh[c + 1];
    h_next[(size_t)r * HH + c]           = tanhf(acc00 + bias0);
    h_next[(size_t)r * HH + c + 1]       = tanhf(acc01 + bias1);
    h_next[(size_t)(r + 1) * HH + c]     = tanhf(acc10 + bias0);
    h_next[(size_t)(r + 1) * HH + c + 1] = tanhf(acc11 + bias1);
}

// out[b][o] = b_fc[o] + sum_k h[b][k] * W_fc[o][k]; grid = B blocks of 256
__global__ __launch_bounds__(256) void fc_kernel(
    const float* __restrict__ h,      // (B, H)
    const float* __restrict__ W_fc,   // (O, H)
    const float* __restrict__ b_fc,   // (O)
    float* __restrict__ out)          // (B, O)
{
    const int b = blockIdx.x;
    const int tid = threadIdx.x;
    float p[OO] = {0.f, 0.f, 0.f, 0.f};
    for (int k = tid; k < HH; k += 256) {
        float hv = h[(size_t)b * HH + k];
        #pragma unroll
        for (int o = 0; o < OO; ++o) p[o] += hv * W_fc[(size_t)o * HH + k];
    }
    #pragma unroll
    for (int off = 32; off > 0; off >>= 1) {
        #pragma unroll
        for (int o = 0; o < OO; ++o) p[o] += __shfl_down(p[o], off, 64);
    }
    __shared__ float red[4][OO];
    const int wave = tid >> 6, lane = tid & 63;
    if (lane == 0) {
        #pragma unroll
        for (int o = 0; o < OO; ++o) red[wave][o] = p[o];
    }
    __syncthreads();
    if (tid < OO) {
        float s = red[0][tid] + red[1][tid] + red[2][tid] + red[3][tid] + b_fc[tid];
        out[b * OO + tid] = s;
    }
}

extern "C" void kernel_launch(void* const* d_in, const int* in_sizes, int n_in,
                              void* d_out, int out_size, void* d_ws, size_t ws_size,
                              hipStream_t stream) {
    const float* x    = (const float*)d_in[0];
    const float* W_ih = (const float*)d_in[1];
    const float* W_hh = (const float*)d_in[2];
    const float* b_ih = (const float*)d_in[3];
    const float* b_hh = (const float*)d_in[4];
    const float* W_fc = (const float*)d_in[5];
    const float* b_fc = (const float*)d_in[6];
    float* out = (float*)d_out;

    float* h0 = (float*)d_ws;
    float* h1 = h0 + (size_t)BB * HH;

    zero_kernel<<<(BB * HH) / 256, 256, 0, stream>>>(h0, BB * HH);

    for (int t = 0; t < TT; ++t) {
        const float* hp = (t & 1) ? h1 : h0;
        float*       hn = (t & 1) ? h0 : h1;
        rnn_step<<<dim3(8, 32), 256, 0, stream>>>(x, W_ih, W_hh, b_ih, b_hh, hp, hn, t);
    }
    // T=224 (even): last write (t=223, odd) went to h0
    fc_kernel<<<BB, 256, 0, stream>>>(h0, W_fc, b_fc, out);
}

// Round 2
// 7010.408 us; speedup vs baseline: 2.1289x; 2.1289x over previous
//
#include <hip/hip_runtime.h>
#include <hip/hip_bf16.h>
#include <cstddef>

#define BB 256
#define TT 224
#define II 224
#define HH 1024
#define OO 4

typedef __attribute__((ext_vector_type(8))) short short8;   // 8 bf16 (4 VGPRs)
typedef __attribute__((ext_vector_type(4))) float f32x4;    // MFMA accumulator

// ---------------------------------------------------------------- utility
__global__ void zero_kernel(float* __restrict__ p, int n) {
    int i = blockIdx.x * blockDim.x + threadIdx.x;
    if (i < n) p[i] = 0.f;
}

// split fp32 -> bf16 hi + bf16 lo (v ~= hi + lo, residual ~2^-17 rel)
__global__ __launch_bounds__(256) void split_hi_lo(
    const float* __restrict__ src, __hip_bfloat16* __restrict__ hi,
    __hip_bfloat16* __restrict__ lo, int n4)
{
    struct bfx4 { __hip_bfloat16 v[4]; };
    const int stride = gridDim.x * blockDim.x;
    for (int i = blockIdx.x * blockDim.x + threadIdx.x; i < n4; i += stride) {
        float4 s = ((const float4*)src)[i];
        float vv[4] = {s.x, s.y, s.z, s.w};
        bfx4 h, l;
        #pragma unroll
        for (int j = 0; j < 4; ++j) {
            __hip_bfloat16 hb = __float2bfloat16(vv[j]);
            h.v[j] = hb;
            l.v[j] = __float2bfloat16(vv[j] - __bfloat162float(hb));
        }
        ((bfx4*)hi)[i] = h;
        ((bfx4*)lo)[i] = l;
    }
}

// ---------------------------------------------------------------- MFMA step
// One wave (64 thr) per 32x32 output tile. grid (8, 32).
// Fragments loaded straight from global (L2-resident); no LDS.
// A row = lane&15, k = (lane>>4)*8 + j ; B col = lane&15, same k
// C/D: col = lane&15, row = (lane>>4)*4 + reg
__global__ __launch_bounds__(64) void rnn_step_mfma(
    const __hip_bfloat16* __restrict__ xh,  const __hip_bfloat16* __restrict__ xl,
    const __hip_bfloat16* __restrict__ wihh, const __hip_bfloat16* __restrict__ wihl,
    const __hip_bfloat16* __restrict__ whhh, const __hip_bfloat16* __restrict__ whhl,
    const __hip_bfloat16* __restrict__ hhp, const __hip_bfloat16* __restrict__ hlp,
    const float* __restrict__ b_ih, const float* __restrict__ b_hh,
    __hip_bfloat16* __restrict__ hhn, __hip_bfloat16* __restrict__ hln,
    float* __restrict__ h32, int t)
{
    const int lane  = threadIdx.x;
    const int row16 = lane & 15;
    const int kblk  = lane >> 4;
    const int r0 = blockIdx.x * 32;
    const int c0 = blockIdx.y * 32;

    f32x4 acc[2][2] = {};

#define MFMA3(m, n, AH, AL, BH, BL)                                             \
    acc[m][n] = __builtin_amdgcn_mfma_f32_16x16x32_bf16(AH, BH, acc[m][n], 0, 0, 0); \
    acc[m][n] = __builtin_amdgcn_mfma_f32_16x16x32_bf16(AH, BL, acc[m][n], 0, 0, 0); \
    acc[m][n] = __builtin_amdgcn_mfma_f32_16x16x32_bf16(AL, BH, acc[m][n], 0, 0, 0);

    // ---- input projection: K over I = 224 ----
    {
        const size_t a0 = ((size_t)(r0 + row16) * TT + t) * II + kblk * 8;
        const size_t a1 = ((size_t)(r0 + 16 + row16) * TT + t) * II + kblk * 8;
        const size_t b0 = (size_t)(c0 + row16) * II + kblk * 8;
        const size_t b1 = (size_t)(c0 + 16 + row16) * II + kblk * 8;
        #pragma unroll
        for (int kb = 0; kb < II; kb += 32) {
            short8 ah0 = *(const short8*)(xh + a0 + kb);
            short8 ah1 = *(const short8*)(xh + a1 + kb);
            short8 al0 = *(const short8*)(xl + a0 + kb);
            short8 al1 = *(const short8*)(xl + a1 + kb);
            short8 bh0 = *(const short8*)(wihh + b0 + kb);
            short8 bh1 = *(const short8*)(wihh + b1 + kb);
            short8 bl0 = *(const short8*)(wihl + b0 + kb);
            short8 bl1 = *(const short8*)(wihl + b1 + kb);
            MFMA3(0, 0, ah0, al0, bh0, bl0)
            MFMA3(0, 1, ah0, al0, bh1, bl1)
            MFMA3(1, 0, ah1, al1, bh0, bl0)
            MFMA3(1, 1, ah1, al1, bh1, bl1)
        }
    }

    // ---- recurrent: K over H = 1024 ----
    {
        const size_t a0 = (size_t)(r0 + row16) * HH + kblk * 8;
        const size_t a1 = (size_t)(r0 + 16 + row16) * HH + kblk * 8;
        const size_t b0 = (size_t)(c0 + row16) * HH + kblk * 8;
        const size_t b1 = (size_t)(c0 + 16 + row16) * HH + kblk * 8;
        #pragma unroll 8
        for (int kb = 0; kb < HH; kb += 32) {
            short8 ah0 = *(const short8*)(hhp + a0 + kb);
            short8 ah1 = *(const short8*)(hhp + a1 + kb);
            short8 al0 = *(const short8*)(hlp + a0 + kb);
            short8 al1 = *(const short8*)(hlp + a1 + kb);
            short8 bh0 = *(const short8*)(whhh + b0 + kb);
            short8 bh1 = *(const short8*)(whhh + b1 + kb);
            short8 bl0 = *(const short8*)(whhl + b0 + kb);
            short8 bl1 = *(const short8*)(whhl + b1 + kb);
            MFMA3(0, 0, ah0, al0, bh0, bl0)
            MFMA3(0, 1, ah0, al0, bh1, bl1)
            MFMA3(1, 0, ah1, al1, bh0, bl0)
            MFMA3(1, 1, ah1, al1, bh1, bl1)
        }
    }
#undef MFMA3

    // ---- epilogue: bias + tanh, write hi/lo bf16 (and fp32 on last step) ----
    #pragma unroll
    for (int n = 0; n < 2; ++n) {
        const int c = c0 + n * 16 + row16;
        const float bias = b_ih[c] + b_hh[c];
        #pragma unroll
        for (int m = 0; m < 2; ++m) {
            #pragma unroll
            for (int j = 0; j < 4; ++j) {
                const int r = r0 + m * 16 + kblk * 4 + j;
                const float v = tanhf(acc[m][n][j] + bias);
                const size_t o = (size_t)r * HH + c;
                __hip_bfloat16 hb = __float2bfloat16(v);
                hhn[o] = hb;
                hln[o] = __float2bfloat16(v - __bfloat162float(hb));
                if (t == TT - 1) h32[o] = v;
            }
        }
    }
}

// ---------------------------------------------------------------- fallback fp32 step (round-0 proven path)
__global__ __launch_bounds__(256) void rnn_step(
    const float* __restrict__ x, const float* __restrict__ W_ih,
    const float* __restrict__ W_hh, const float* __restrict__ b_ih,
    const float* __restrict__ b_hh, const float* __restrict__ h_prev,
    float* __restrict__ h_next, int t)
{
    __shared__ float As[32][33];
    __shared__ float Bs[32][33];
    const int r0 = blockIdx.x * 32;
    const int c0 = blockIdx.y * 32;
    const int tid = threadIdx.x;
    const int tr = tid >> 4;
    const int tc = tid & 15;
    float acc00 = 0.f, acc01 = 0.f, acc10 = 0.f, acc11 = 0.f;
    for (int kb = 0; kb < II; kb += 32) {
        #pragma unroll
        for (int l = 0; l < 4; ++l) {
            int idx = tid + l * 256;
            int r = idx >> 5, k = idx & 31;
            As[r][k] = x[((size_t)(r0 + r) * TT + t) * II + kb + k];
            Bs[r][k] = W_ih[(size_t)(c0 + r) * II + kb + k];
        }
        __syncthreads();
        #pragma unroll 8
        for (int k = 0; k < 32; ++k) {
            float a0 = As[2*tr][k], a1 = As[2*tr+1][k];
            float b0 = Bs[2*tc][k], b1 = Bs[2*tc+1][k];
            acc00 += a0 * b0; acc01 += a0 * b1;
            acc10 += a1 * b0; acc11 += a1 * b1;
        }
        __syncthreads();
    }
    for (int kb = 0; kb < HH; kb += 32) {
        #pragma unroll
        for (int l = 0; l < 4; ++l) {
            int idx = tid + l * 256;
            int r = idx >> 5, k = idx & 31;
            As[r][k] = h_prev[(size_t)(r0 + r) * HH + kb + k];
            Bs[r][k] = W_hh[(size_t)(c0 + r) * HH + kb + k];
        }
        __syncthreads();
        #pragma unroll 8
        for (int k = 0; k < 32; ++k) {
            float a0 = As[2*tr][k], a1 = As[2*tr+1][k];
            float b0 = Bs[2*tc][k], b1 = Bs[2*tc+1][k];
            acc00 += a0 * b0; acc01 += a0 * b1;
            acc10 += a1 * b0; acc11 += a1 * b1;
        }
        __syncthreads();
    }
    const int r = r0 + 2 * tr;
    const int c = c0 + 2 * tc;
    const float bias0 = b_ih[c] + b_hh[c];
    const float bias1 = b_ih[c + 1] + b_hh[c + 1];
    h_next[(size_t)r * HH + c]           = tanhf(acc00 + bias0);
    h_next[(size_t)r * HH + c + 1]       = tanhf(acc01 + bias1);
    h_next[(size_t)(r + 1) * HH + c]     = tanhf(acc10 + bias0);
    h_next[(size_t)(r + 1) * HH + c + 1] = tanhf(acc11 + bias1);
}

// ---------------------------------------------------------------- FC
__global__ __launch_bounds__(256) void fc_kernel(
    const float* __restrict__ h, const float* __restrict__ W_fc,
    const float* __restrict__ b_fc, float* __restrict__ out)
{
    const int b = blockIdx.x;
    const int tid = threadIdx.x;
    float p[OO] = {0.f, 0.f, 0.f, 0.f};
    for (int k = tid; k < HH; k += 256) {
        float hv = h[(size_t)b * HH + k];
        #pragma unroll
        for (int o = 0; o < OO; ++o) p[o] += hv * W_fc[(size_t)o * HH + k];
    }
    #pragma unroll
    for (int off = 32; off > 0; off >>= 1) {
        #pragma unroll
        for (int o = 0; o < OO; ++o) p[o] += __shfl_down(p[o], off, 64);
    }
    __shared__ float red[4][OO];
    const int wave = tid >> 6, lane = tid & 63;
    if (lane == 0) {
        #pragma unroll
        for (int o = 0; o < OO; ++o) red[wave][o] = p[o];
    }
    __syncthreads();
    if (tid < OO) {
        float s = red[0][tid] + red[1][tid] + red[2][tid] + red[3][tid] + b_fc[tid];
        out[b * OO + tid] = s;
    }
}

// ---------------------------------------------------------------- launch
extern "C" void kernel_launch(void* const* d_in, const int* in_sizes, int n_in,
                              void* d_out, int out_size, void* d_ws, size_t ws_size,
                              hipStream_t stream) {
    const float* x    = (const float*)d_in[0];
    const float* W_ih = (const float*)d_in[1];
    const float* W_hh = (const float*)d_in[2];
    const float* b_ih = (const float*)d_in[3];
    const float* b_hh = (const float*)d_in[4];
    const float* W_fc = (const float*)d_in[5];
    const float* b_fc = (const float*)d_in[6];
    float* out = (float*)d_out;

    // ws layout (bytes)
    const size_t SZ_X   = (size_t)BB * TT * II * 2;   // one bf16 plane of x
    const size_t SZ_WIH = (size_t)HH * II * 2;
    const size_t SZ_WHH = (size_t)HH * HH * 2;
    const size_t SZ_H   = (size_t)BB * HH * 2;        // one bf16 plane of h
    const size_t OFF_XH   = 0;
    const size_t OFF_XL   = OFF_XH + SZ_X;
    const size_t OFF_WIHH = OFF_XL + SZ_X;
    const size_t OFF_WIHL = OFF_WIHH + SZ_WIH;
    const size_t OFF_WHHH = OFF_WIHL + SZ_WIH;
    const size_t OFF_WHHL = OFF_WHHH + SZ_WHH;
    const size_t OFF_HH0  = OFF_WHHL + SZ_WHH;
    const size_t OFF_HL0  = OFF_HH0 + SZ_H;
    const size_t OFF_HH1  = OFF_HL0 + SZ_H;
    const size_t OFF_HL1  = OFF_HH1 + SZ_H;
    const size_t OFF_H32  = OFF_HL1 + SZ_H;
    const size_t NEED     = OFF_H32 + (size_t)BB * HH * 4;

    char* ws = (char*)d_ws;

    if (ws_size >= NEED) {
        __hip_bfloat16* xhp   = (__hip_bfloat16*)(ws + OFF_XH);
        __hip_bfloat16* xlp   = (__hip_bfloat16*)(ws + OFF_XL);
        __hip_bfloat16* wihh  = (__hip_bfloat16*)(ws + OFF_WIHH);
        __hip_bfloat16* wihl  = (__hip_bfloat16*)(ws + OFF_WIHL);
        __hip_bfloat16* whhh  = (__hip_bfloat16*)(ws + OFF_WHHH);
        __hip_bfloat16* whhl  = (__hip_bfloat16*)(ws + OFF_WHHL);
        __hip_bfloat16* hh[2] = {(__hip_bfloat16*)(ws + OFF_HH0), (__hip_bfloat16*)(ws + OFF_HH1)};
        __hip_bfloat16* hl[2] = {(__hip_bfloat16*)(ws + OFF_HL0), (__hip_bfloat16*)(ws + OFF_HL1)};
        float* h32 = (float*)(ws + OFF_H32);

        // one-time (per call) precision splits
        split_hi_lo<<<1024, 256, 0, stream>>>(x, xhp, xlp, (BB * TT * II) / 4);
        split_hi_lo<<<128, 256, 0, stream>>>(W_ih, wihh, wihl, (HH * II) / 4);
        split_hi_lo<<<512, 256, 0, stream>>>(W_hh, whhh, whhl, (HH * HH) / 4);
        // zero h0 planes (hh0 + hl0 contiguous = 1 MB)
        zero_kernel<<<(int)((2 * SZ_H / 4 + 255) / 256), 256, 0, stream>>>((float*)(ws + OFF_HH0), (int)(2 * SZ_H / 4));

        for (int t = 0; t < TT; ++t) {
            const int p = t & 1, q = p ^ 1;
            rnn_step_mfma<<<dim3(8, 32), 64, 0, stream>>>(
                xhp, xlp, wihh, wihl, whhh, whhl,
                hh[p], hl[p], b_ih, b_hh, hh[q], hl[q], h32, t);
        }
        fc_kernel<<<BB, 256, 0, stream>>>(h32, W_fc, b_fc, out);
    } else {
        // fallback: proven fp32 path
        float* h0 = (float*)d_ws;
        float* h1 = h0 + (size_t)BB * HH;
        zero_kernel<<<(BB * HH) / 256, 256, 0, stream>>>(h0, BB * HH);
        for (int t = 0; t < TT; ++t) {
            const float* hp = (t & 1) ? h1 : h0;
            float*       hn = (t & 1) ? h0 : h1;
            rnn_step<<<dim3(8, 32), 256, 0, stream>>>(x, W_ih, W_hh, b_ih, b_hh, hp, hn, t);
        }
        fc_kernel<<<BB, 256, 0, stream>>>(h0, W_fc, b_fc, out);
    }
}

// Round 3
// 2954.216 us; speedup vs baseline: 5.0518x; 2.3730x over previous
//
#include <hip/hip_runtime.h>
#include <hip/hip_bf16.h>
#include <cstddef>

#define BB 256
#define TT 224
#define II 224
#define HH 1024
#define OO 4

typedef __attribute__((ext_vector_type(8))) short short8;   // 8 bf16 (4 VGPRs)
typedef __attribute__((ext_vector_type(4))) float f32x4;    // MFMA accumulator

// ---------------------------------------------------------------- utility
__global__ void zero_kernel(float* __restrict__ p, int n) {
    int i = blockIdx.x * blockDim.x + threadIdx.x;
    if (i < n) p[i] = 0.f;
}

// split fp32 -> bf16 hi + bf16 lo (v ~= hi + lo, residual ~2^-17 rel)
__global__ __launch_bounds__(256) void split_hi_lo(
    const float* __restrict__ src, __hip_bfloat16* __restrict__ hi,
    __hip_bfloat16* __restrict__ lo, int n4)
{
    struct bfx4 { __hip_bfloat16 v[4]; };
    const int stride = gridDim.x * blockDim.x;
    for (int i = blockIdx.x * blockDim.x + threadIdx.x; i < n4; i += stride) {
        float4 s = ((const float4*)src)[i];
        float vv[4] = {s.x, s.y, s.z, s.w};
        bfx4 h, l;
        #pragma unroll
        for (int j = 0; j < 4; ++j) {
            __hip_bfloat16 hb = __float2bfloat16(vv[j]);
            h.v[j] = hb;
            l.v[j] = __float2bfloat16(vv[j] - __bfloat162float(hb));
        }
        ((bfx4*)hi)[i] = h;
        ((bfx4*)lo)[i] = l;
    }
}

// ---------------------------------------------------------------- MFMA step (R2)
// 256 WGs x 256 thr (4 waves). Each WG owns a 32x32 output tile; the 4 waves
// K-split the unified K = 224 (input proj) + 1024 (recurrent) = 39 kblocks of 32,
// partials reduced through padded LDS.
// XCD-aware remap: q = lid&7 (assumed XCD) owns col-tiles 4q..4q+3 so the
// W_hh hi/lo slice (512 KB) stays L2-resident across all timesteps.
__global__ __launch_bounds__(256) void rnn_step_mfma2(
    const __hip_bfloat16* __restrict__ xh,   const __hip_bfloat16* __restrict__ xl,
    const __hip_bfloat16* __restrict__ wihh, const __hip_bfloat16* __restrict__ wihl,
    const __hip_bfloat16* __restrict__ whhh, const __hip_bfloat16* __restrict__ whhl,
    const __hip_bfloat16* __restrict__ hhp,  const __hip_bfloat16* __restrict__ hlp,
    const float* __restrict__ b_ih, const float* __restrict__ b_hh,
    __hip_bfloat16* __restrict__ hhn, __hip_bfloat16* __restrict__ hln,
    float* __restrict__ h32, int t)
{
    __shared__ float red[4][32][33];   // +1 pad: conflict-free partial-sum buffer

    const int tid   = threadIdx.x;
    const int wv    = tid >> 6;        // wave 0..3
    const int lane  = tid & 63;
    const int row16 = lane & 15;
    const int kblk  = lane >> 4;       // 0..3

    // XCD-aware tile remap (perf heuristic only)
    const int lid = blockIdx.x + blockIdx.y * gridDim.x;  // 0..255
    const int q   = lid & 7;
    const int j   = lid >> 3;          // 0..31
    const int r0  = (j >> 2) * 32;     // row-tile 0..7
    const int c0  = ((q << 2) | (j & 3)) * 32;  // col-tile 0..31, pinned to XCD q

    f32x4 acc[2][2] = {};

#define MFMA3(m, n, AH, AL, BH, BL)                                                   \
    acc[m][n] = __builtin_amdgcn_mfma_f32_16x16x32_bf16(AH, BH, acc[m][n], 0, 0, 0);  \
    acc[m][n] = __builtin_amdgcn_mfma_f32_16x16x32_bf16(AH, BL, acc[m][n], 0, 0, 0);  \
    acc[m][n] = __builtin_amdgcn_mfma_f32_16x16x32_bf16(AL, BH, acc[m][n], 0, 0, 0);

    // unified kblock range for this wave: [wv*10, min(wv*10+10, 39))
    const int kb_beg = wv * 10;
    const int kb_end = (kb_beg + 10 < 39) ? kb_beg + 10 : 39;

    // ---- input-projection part (kblocks 0..6, K over I=224) ----
    {
        const int xb_beg = (kb_beg < 7) ? kb_beg : 7;
        const int xb_end = (kb_end < 7) ? kb_end : 7;
        const size_t a0 = ((size_t)(r0 + row16) * TT + t) * II + kblk * 8;
        const size_t a1 = ((size_t)(r0 + 16 + row16) * TT + t) * II + kblk * 8;
        const size_t b0 = (size_t)(c0 + row16) * II + kblk * 8;
        const size_t b1 = (size_t)(c0 + 16 + row16) * II + kblk * 8;
        for (int kb = xb_beg; kb < xb_end; ++kb) {
            const int k = kb * 32;
            short8 ah0 = *(const short8*)(xh + a0 + k);
            short8 ah1 = *(const short8*)(xh + a1 + k);
            short8 al0 = *(const short8*)(xl + a0 + k);
            short8 al1 = *(const short8*)(xl + a1 + k);
            short8 bh0 = *(const short8*)(wihh + b0 + k);
            short8 bh1 = *(const short8*)(wihh + b1 + k);
            short8 bl0 = *(const short8*)(wihl + b0 + k);
            short8 bl1 = *(const short8*)(wihl + b1 + k);
            MFMA3(0, 0, ah0, al0, bh0, bl0)
            MFMA3(0, 1, ah0, al0, bh1, bl1)
            MFMA3(1, 0, ah1, al1, bh0, bl0)
            MFMA3(1, 1, ah1, al1, bh1, bl1)
        }
    }

    // ---- recurrent part (kblocks 7..38, K over H=1024) ----
    {
        const int hb_beg = ((kb_beg > 7) ? kb_beg : 7) - 7;
        const int hb_end = kb_end - 7;
        const size_t a0 = (size_t)(r0 + row16) * HH + kblk * 8;
        const size_t a1 = (size_t)(r0 + 16 + row16) * HH + kblk * 8;
        const size_t b0 = (size_t)(c0 + row16) * HH + kblk * 8;
        const size_t b1 = (size_t)(c0 + 16 + row16) * HH + kblk * 8;
        #pragma unroll 5
        for (int kb = hb_beg; kb < hb_end; ++kb) {
            const int k = kb * 32;
            short8 ah0 = *(const short8*)(hhp + a0 + k);
            short8 ah1 = *(const short8*)(hhp + a1 + k);
            short8 al0 = *(const short8*)(hlp + a0 + k);
            short8 al1 = *(const short8*)(hlp + a1 + k);
            short8 bh0 = *(const short8*)(whhh + b0 + k);
            short8 bh1 = *(const short8*)(whhh + b1 + k);
            short8 bl0 = *(const short8*)(whhl + b0 + k);
            short8 bl1 = *(const short8*)(whhl + b1 + k);
            MFMA3(0, 0, ah0, al0, bh0, bl0)
            MFMA3(0, 1, ah0, al0, bh1, bl1)
            MFMA3(1, 0, ah1, al1, bh0, bl0)
            MFMA3(1, 1, ah1, al1, bh1, bl1)
        }
    }
#undef MFMA3

    // ---- cross-wave reduction through LDS ----
    // C/D layout: local col = n*16 + row16, local row = m*16 + kblk*4 + jj
    #pragma unroll
    for (int m = 0; m < 2; ++m)
        #pragma unroll
        for (int n = 0; n < 2; ++n)
            #pragma unroll
            for (int jj = 0; jj < 4; ++jj)
                red[wv][m * 16 + kblk * 4 + jj][n * 16 + row16] = acc[m][n][jj];
    __syncthreads();

    // each wave finalizes one 16x16 quadrant: m = wv>>1, n = wv&1
    {
        const int m = wv >> 1, n = wv & 1;
        const int lc = n * 16 + row16;
        const int c  = c0 + lc;
        const float bias = b_ih[c] + b_hh[c];
        #pragma unroll
        for (int jj = 0; jj < 4; ++jj) {
            const int lr = m * 16 + kblk * 4 + jj;
            float v = red[0][lr][lc] + red[1][lr][lc] + red[2][lr][lc] + red[3][lr][lc] + bias;
            v = tanhf(v);
            const size_t o = (size_t)(r0 + lr) * HH + c;
            __hip_bfloat16 hb = __float2bfloat16(v);
            hhn[o] = hb;
            hln[o] = __float2bfloat16(v - __bfloat162float(hb));
            if (t == TT - 1) h32[o] = v;
        }
    }
}

// ---------------------------------------------------------------- fallback fp32 step (round-0 proven path)
__global__ __launch_bounds__(256) void rnn_step(
    const float* __restrict__ x, const float* __restrict__ W_ih,
    const float* __restrict__ W_hh, const float* __restrict__ b_ih,
    const float* __restrict__ b_hh, const float* __restrict__ h_prev,
    float* __restrict__ h_next, int t)
{
    __shared__ float As[32][33];
    __shared__ float Bs[32][33];
    const int r0 = blockIdx.x * 32;
    const int c0 = blockIdx.y * 32;
    const int tid = threadIdx.x;
    const int tr = tid >> 4;
    const int tc = tid & 15;
    float acc00 = 0.f, acc01 = 0.f, acc10 = 0.f, acc11 = 0.f;
    for (int kb = 0; kb < II; kb += 32) {
        #pragma unroll
        for (int l = 0; l < 4; ++l) {
            int idx = tid + l * 256;
            int r = idx >> 5, k = idx & 31;
            As[r][k] = x[((size_t)(r0 + r) * TT + t) * II + kb + k];
            Bs[r][k] = W_ih[(size_t)(c0 + r) * II + kb + k];
        }
        __syncthreads();
        #pragma unroll 8
        for (int k = 0; k < 32; ++k) {
            float a0 = As[2*tr][k], a1 = As[2*tr+1][k];
            float b0 = Bs[2*tc][k], b1 = Bs[2*tc+1][k];
            acc00 += a0 * b0; acc01 += a0 * b1;
            acc10 += a1 * b0; acc11 += a1 * b1;
        }
        __syncthreads();
    }
    for (int kb = 0; kb < HH; kb += 32) {
        #pragma unroll
        for (int l = 0; l < 4; ++l) {
            int idx = tid + l * 256;
            int r = idx >> 5, k = idx & 31;
            As[r][k] = h_prev[(size_t)(r0 + r) * HH + kb + k];
            Bs[r][k] = W_hh[(size_t)(c0 + r) * HH + kb + k];
        }
        __syncthreads();
        #pragma unroll 8
        for (int k = 0; k < 32; ++k) {
            float a0 = As[2*tr][k], a1 = As[2*tr+1][k];
            float b0 = Bs[2*tc][k], b1 = Bs[2*tc+1][k];
            acc00 += a0 * b0; acc01 += a0 * b1;
            acc10 += a1 * b0; acc11 += a1 * b1;
        }
        __syncthreads();
    }
    const int r = r0 + 2 * tr;
    const int c = c0 + 2 * tc;
    const float bias0 = b_ih[c] + b_hh[c];
    const float bias1 = b_ih[c + 1] + b_hh[c + 1];
    h_next[(size_t)r * HH + c]           = tanhf(acc00 + bias0);
    h_next[(size_t)r * HH + c + 1]       = tanhf(acc01 + bias1);
    h_next[(size_t)(r + 1) * HH + c]     = tanhf(acc10 + bias0);
    h_next[(size_t)(r + 1) * HH + c + 1] = tanhf(acc11 + bias1);
}

// ---------------------------------------------------------------- FC
__global__ __launch_bounds__(256) void fc_kernel(
    const float* __restrict__ h, const float* __restrict__ W_fc,
    const float* __restrict__ b_fc, float* __restrict__ out)
{
    const int b = blockIdx.x;
    const int tid = threadIdx.x;
    float p[OO] = {0.f, 0.f, 0.f, 0.f};
    for (int k = tid; k < HH; k += 256) {
        float hv = h[(size_t)b * HH + k];
        #pragma unroll
        for (int o = 0; o < OO; ++o) p[o] += hv * W_fc[(size_t)o * HH + k];
    }
    #pragma unroll
    for (int off = 32; off > 0; off >>= 1) {
        #pragma unroll
        for (int o = 0; o < OO; ++o) p[o] += __shfl_down(p[o], off, 64);
    }
    __shared__ float red[4][OO];
    const int wave = tid >> 6, lane = tid & 63;
    if (lane == 0) {
        #pragma unroll
        for (int o = 0; o < OO; ++o) red[wave][o] = p[o];
    }
    __syncthreads();
    if (tid < OO) {
        float s = red[0][tid] + red[1][tid] + red[2][tid] + red[3][tid] + b_fc[tid];
        out[b * OO + tid] = s;
    }
}

// ---------------------------------------------------------------- launch
extern "C" void kernel_launch(void* const* d_in, const int* in_sizes, int n_in,
                              void* d_out, int out_size, void* d_ws, size_t ws_size,
                              hipStream_t stream) {
    const float* x    = (const float*)d_in[0];
    const float* W_ih = (const float*)d_in[1];
    const float* W_hh = (const float*)d_in[2];
    const float* b_ih = (const float*)d_in[3];
    const float* b_hh = (const float*)d_in[4];
    const float* W_fc = (const float*)d_in[5];
    const float* b_fc = (const float*)d_in[6];
    float* out = (float*)d_out;

    // ws layout (bytes)
    const size_t SZ_X   = (size_t)BB * TT * II * 2;   // one bf16 plane of x
    const size_t SZ_WIH = (size_t)HH * II * 2;
    const size_t SZ_WHH = (size_t)HH * HH * 2;
    const size_t SZ_H   = (size_t)BB * HH * 2;        // one bf16 plane of h
    const size_t OFF_XH   = 0;
    const size_t OFF_XL   = OFF_XH + SZ_X;
    const size_t OFF_WIHH = OFF_XL + SZ_X;
    const size_t OFF_WIHL = OFF_WIHH + SZ_WIH;
    const size_t OFF_WHHH = OFF_WIHL + SZ_WIH;
    const size_t OFF_WHHL = OFF_WHHH + SZ_WHH;
    const size_t OFF_HH0  = OFF_WHHL + SZ_WHH;
    const size_t OFF_HL0  = OFF_HH0 + SZ_H;
    const size_t OFF_HH1  = OFF_HL0 + SZ_H;
    const size_t OFF_HL1  = OFF_HH1 + SZ_H;
    const size_t OFF_H32  = OFF_HL1 + SZ_H;
    const size_t NEED     = OFF_H32 + (size_t)BB * HH * 4;

    char* ws = (char*)d_ws;

    if (ws_size >= NEED) {
        __hip_bfloat16* xhp   = (__hip_bfloat16*)(ws + OFF_XH);
        __hip_bfloat16* xlp   = (__hip_bfloat16*)(ws + OFF_XL);
        __hip_bfloat16* wihh  = (__hip_bfloat16*)(ws + OFF_WIHH);
        __hip_bfloat16* wihl  = (__hip_bfloat16*)(ws + OFF_WIHL);
        __hip_bfloat16* whhh  = (__hip_bfloat16*)(ws + OFF_WHHH);
        __hip_bfloat16* whhl  = (__hip_bfloat16*)(ws + OFF_WHHL);
        __hip_bfloat16* hh[2] = {(__hip_bfloat16*)(ws + OFF_HH0), (__hip_bfloat16*)(ws + OFF_HH1)};
        __hip_bfloat16* hl[2] = {(__hip_bfloat16*)(ws + OFF_HL0), (__hip_bfloat16*)(ws + OFF_HL1)};
        float* h32 = (float*)(ws + OFF_H32);

        // one-time (per call) precision splits
        split_hi_lo<<<1024, 256, 0, stream>>>(x, xhp, xlp, (BB * TT * II) / 4);
        split_hi_lo<<<128, 256, 0, stream>>>(W_ih, wihh, wihl, (HH * II) / 4);
        split_hi_lo<<<512, 256, 0, stream>>>(W_hh, whhh, whhl, (HH * HH) / 4);
        // zero h0 planes (hh0 + hl0 contiguous = 1 MB)
        zero_kernel<<<(int)((2 * SZ_H / 4 + 255) / 256), 256, 0, stream>>>((float*)(ws + OFF_HH0), (int)(2 * SZ_H / 4));

        for (int t = 0; t < TT; ++t) {
            const int p = t & 1, q = p ^ 1;
            rnn_step_mfma2<<<dim3(8, 32), 256, 0, stream>>>(
                xhp, xlp, wihh, wihl, whhh, whhl,
                hh[p], hl[p], b_ih, b_hh, hh[q], hl[q], h32, t);
        }
        fc_kernel<<<BB, 256, 0, stream>>>(h32, W_fc, b_fc, out);
    } else {
        // fallback: proven fp32 path
        float* h0 = (float*)d_ws;
        float* h1 = h0 + (size_t)BB * HH;
        zero_kernel<<<(BB * HH) / 256, 256, 0, stream>>>(h0, BB * HH);
        for (int t = 0; t < TT; ++t) {
            const float* hp = (t & 1) ? h1 : h0;
            float*       hn = (t & 1) ? h0 : h1;
            rnn_step<<<dim3(8, 32), 256, 0, stream>>>(x, W_ih, W_hh, b_ih, b_hh, hp, hn, t);
        }
        fc_kernel<<<BB, 256, 0, stream>>>(h0, W_fc, b_fc, out);
    }
}